// Round 13
// baseline (188.881 us; speedup 1.0000x reference)
//
#include <hip/hip_runtime.h>
#include <hip/hip_cooperative_groups.h>

// K-manifold AE cluster objective — ROUND 13: single cooperative dispatch.
// out = mean_b min_k [ ||x_b||^2 - 2 w.z + z^T G z + lamb*reg_k ]
// Phase A: A-stage + distributed W-pack + G/lreg  -> grid.sync()
// Phase B: MFMA GEMM (global_load_lds DMA, counted vmcnt) + wave-local epilogue
// Phase C: grid.sync() -> block 0 reduces partials -> out
// Fallback (if cooperative launch fails, e.g. under capture): round-10 2-kernel path.

#define KCLUST   16
#define DAMB     512
#define DLAT     10
#define BATCH    16384
#define LAMBDA   0.01f

#define BM       64
#define NTHREADS 512           // 8 waves: 2M x 4N
#define NKS      16
#define NNT      20
#define NBLK     (BATCH / BM)  // 256
#define CHB      40960         // bytes per B chunk (2 ks x 20 nt x 64 x 16B)
#define SSTR     84

typedef __attribute__((ext_vector_type(8))) short short8;
typedef __attribute__((ext_vector_type(4))) float f32x4;

__device__ inline short f2bf(float f) {
    unsigned u = __builtin_bit_cast(unsigned, f);
    unsigned r = (u + 0x7FFFu + ((u >> 16) & 1u)) >> 16;
    return (short)r;
}

__device__ __forceinline__ void gload_lds16(const void* g, void* l) {
    __builtin_amdgcn_global_load_lds(
        (const __attribute__((address_space(1))) unsigned int*)g,
        (__attribute__((address_space(3))) unsigned int*)l, 16, 0, 0);
}

template <int N> __device__ __forceinline__ void waitv() {
    if constexpr (N == 0)      asm volatile("s_waitcnt vmcnt(0)" ::: "memory");
    else if constexpr (N == 5) asm volatile("s_waitcnt vmcnt(5)" ::: "memory");
    __builtin_amdgcn_sched_barrier(0);   // rule #18
}

// W fragment-row packer: row idx in [0, 20480)
__device__ __forceinline__ void pack_w_row(const float* __restrict__ Us,
                                           const float* __restrict__ Vs,
                                           short* __restrict__ wpack, int idx) {
    int ks   = idx / (NNT * 64);
    int rem  = idx % (NNT * 64);
    int nt   = rem / 64;
    int lane = rem % 64;
    int col  = nt * 16 + (lane & 15);
    int cl   = col / 20;
    int c    = col % 20;
    short8 sv;
#pragma unroll
    for (int j = 0; j < 8; ++j) {
        int k = ks * 32 + (lane >> 4) * 8 + j;
        float v;
        if (c < DLAT) v = Vs[(size_t)cl * DLAT * DAMB + c * DAMB + k];
        else          v = Us[(size_t)cl * DAMB * DLAT + k * DLAT + (c - DLAT)];
        sv[j] = f2bf(v);
    }
    *(short8*)&wpack[(size_t)idx * 8] = sv;
}

// ==================== single cooperative kernel ====================
__global__ __launch_bounds__(NTHREADS) void fused_k(const float* __restrict__ x,
                                                    const float* __restrict__ Us,
                                                    const float* __restrict__ Vs,
                                                    short* __restrict__ wpack,
                                                    float* __restrict__ G,
                                                    float* __restrict__ lreg,
                                                    float* __restrict__ parts,
                                                    float* __restrict__ out) {
    cooperative_groups::grid_group grid = cooperative_groups::this_grid();

    __shared__ __align__(16) char a_region[65536];    // A frags; epilogue strips
    __shared__ __align__(16) char b_region[2 * CHB];  // B dbuf; gpart / objl
    __shared__ float Gs[KCLUST * 100];
    __shared__ float lregs[KCLUST];
    __shared__ float rsqp[BM][8];
    __shared__ float rowsq_s[BM];
    __shared__ float sred[8];

    short* a_lds = (short*)a_region;
    float* sbuf  = (float*)a_region;
    float (*objl)[17] = (float(*)[17])b_region;
    float* gpart = (float*)b_region;                  // Phase-A scratch (500 floats)

    const int tid  = threadIdx.x;
    const int lane = tid & 63;
    const int wv   = tid >> 6;
    const int mw   = wv >> 2;
    const int nw   = wv & 3;
    const int bid  = blockIdx.x;
    const int row0 = bid * BM;

    // ---- Phase A1: stage A (fp32 -> bf16, fragment order) + exact rowsq
    {
        const int srow = tid >> 3;
        const int sc   = tid & 7;
        const int mt   = srow >> 4;
        const int rlo  = srow & 15;
        const float* xr = x + (size_t)(row0 + srow) * DAMB;
        float rs = 0.f;
#pragma unroll
        for (int i = 0; i < 8; ++i) {
            int k8 = sc + 8 * i;
            float4 v0 = *(const float4*)(xr + k8 * 8);
            float4 v1 = *(const float4*)(xr + k8 * 8 + 4);
            rs += v0.x * v0.x + v0.y * v0.y + v0.z * v0.z + v0.w * v0.w
                + v1.x * v1.x + v1.y * v1.y + v1.z * v1.z + v1.w * v1.w;
            short8 sv;
            sv[0] = f2bf(v0.x); sv[1] = f2bf(v0.y); sv[2] = f2bf(v0.z); sv[3] = f2bf(v0.w);
            sv[4] = f2bf(v1.x); sv[5] = f2bf(v1.y); sv[6] = f2bf(v1.z); sv[7] = f2bf(v1.w);
            int ks = k8 >> 2, lh = k8 & 3;
            int ln = (lh << 4) | rlo;
            *(short8*)&a_lds[((mt * NKS + ks) * 64 + ln) * 8] = sv;
        }
        rsqp[srow][sc] = rs;
    }
    __syncthreads();
    if (tid < BM) {
        float s = 0.f;
#pragma unroll
        for (int j = 0; j < 8; ++j) s += rsqp[tid][j];
        rowsq_s[tid] = s;
    }

    // ---- Phase A2: distributed W pack (80 fragment-rows per block)
    if (tid < 80) pack_w_row(Us, Vs, wpack, bid * 80 + tid);

    // ---- Phase A3: blocks 0..15 compute lreg + G for cluster bid
    if (bid < KCLUST) {
        const float* Uk = Us + (size_t)bid * DAMB * DLAT;
        const float* Vk = Vs + (size_t)bid * DLAT * DAMB;
        float s = 0.f;
        for (int i = tid; i < DAMB * DLAT; i += NTHREADS) {
            float a = Uk[i], b = Vk[i];
            s += a * a + b * b;
        }
#pragma unroll
        for (int off = 32; off > 0; off >>= 1) s += __shfl_down(s, off);
        if (lane == 0) sred[wv] = s;
        __syncthreads();
        if (tid == 0) {
            float t = 0.f;
#pragma unroll
            for (int j = 0; j < 8; ++j) t += sred[j];
            lreg[bid] = (LAMBDA * 0.5f) * t;
        }
        if (tid < 500) {
            int e = tid / 5, dp = tid % 5;
            int i = e / DLAT, j = e % DLAT;
            int d0 = dp * 102 + (dp < 2 ? dp : 2);
            int d1 = d0 + 102 + (dp < 2 ? 1 : 0);
            float g = 0.f;
            for (int d = d0; d < d1; ++d)
                g = fmaf(Uk[d * DLAT + i], Uk[d * DLAT + j], g);
            gpart[tid] = g;
        }
        __syncthreads();
        if (tid < 100) {
            float g = gpart[tid * 5] + gpart[tid * 5 + 1] + gpart[tid * 5 + 2]
                    + gpart[tid * 5 + 3] + gpart[tid * 5 + 4];
            G[bid * 100 + tid] = g;
        }
    }

    __threadfence();
    grid.sync();                 // wpack/G/lreg visible device-wide

    // ---- Phase B0: stage G/lreg to LDS; barrier drains vmcnt for counted waits
    for (int i = tid; i < KCLUST * 100; i += NTHREADS) Gs[i] = G[i];
    if (tid < KCLUST) lregs[tid] = lreg[tid];
    __syncthreads();

    // ---- Phase B1: K loop (r10-proven: DMA staging, counted vmcnt, raw barriers)
    f32x4 acc[2][5];
#pragma unroll
    for (int m = 0; m < 2; ++m)
#pragma unroll
        for (int j = 0; j < 5; ++j) acc[m][j] = (f32x4)0.f;

    const char* wsrc = (const char*)wpack;
    const int soff = (wv * 5) * 1024 + lane * 16;

#define ISSUE(c) do { \
        const char* s_ = wsrc + (size_t)(c) * CHB + soff; \
        char* d_ = b_region + ((c) & 1) * CHB + soff; \
        gload_lds16(s_ + 0,    d_ + 0); \
        gload_lds16(s_ + 1024, d_ + 1024); \
        gload_lds16(s_ + 2048, d_ + 2048); \
        gload_lds16(s_ + 3072, d_ + 3072); \
        gload_lds16(s_ + 4096, d_ + 4096); \
        __builtin_amdgcn_sched_barrier(0); \
    } while (0)

#define KSTEP(c, VM) do { \
        waitv<VM>(); \
        __builtin_amdgcn_s_barrier(); \
        __builtin_amdgcn_sched_barrier(0); \
        const short* B_ = (const short*)(b_region + ((c) & 1) * CHB); \
        _Pragma("unroll") \
        for (int ksl = 0; ksl < 2; ++ksl) { \
            short8 a0 = *(short8*)&a_lds[(((mw * 2 + 0) * NKS + (c) * 2 + ksl) * 64 + lane) * 8]; \
            short8 a1 = *(short8*)&a_lds[(((mw * 2 + 1) * NKS + (c) * 2 + ksl) * 64 + lane) * 8]; \
            _Pragma("unroll") \
            for (int j = 0; j < 5; ++j) { \
                short8 bf = *(short8*)&B_[((ksl * NNT + nw * 5 + j) * 64 + lane) * 8]; \
                acc[0][j] = __builtin_amdgcn_mfma_f32_16x16x32_bf16(a0, bf, acc[0][j], 0, 0, 0); \
                acc[1][j] = __builtin_amdgcn_mfma_f32_16x16x32_bf16(a1, bf, acc[1][j], 0, 0, 0); \
            } \
        } \
        __builtin_amdgcn_sched_barrier(0); \
        __builtin_amdgcn_s_barrier(); \
        __builtin_amdgcn_sched_barrier(0); \
    } while (0)

    ISSUE(0); ISSUE(1);
    KSTEP(0, 5); ISSUE(2);
    KSTEP(1, 5); ISSUE(3);
    KSTEP(2, 5); ISSUE(4);
    KSTEP(3, 5); ISSUE(5);
    KSTEP(4, 5); ISSUE(6);
    KSTEP(5, 5); ISSUE(7);
    KSTEP(6, 5);
    KSTEP(7, 0);

#undef KSTEP
#undef ISSUE

    // ---- Phase B2: wave-local epilogue (r10-proven)
    const int stro = wv * (16 * SSTR);
#pragma unroll
    for (int m = 0; m < 2; ++m) {
        int rowb = (lane >> 4) * 4;
#pragma unroll
        for (int j = 0; j < 5; ++j) {
            int colb = j * 16 + (lane & 15);
#pragma unroll
            for (int r = 0; r < 4; ++r)
                sbuf[stro + (rowb + r) * SSTR + colb] = acc[m][j][r];
        }
        {
            int rowl = lane >> 2;
            int cl   = lane & 3;
            const float* yy = sbuf + stro + rowl * SSTR + cl * 20;
            float4 v0 = *(const float4*)(yy + 0);
            float4 v1 = *(const float4*)(yy + 4);
            float4 v2 = *(const float4*)(yy + 8);
            float4 v3 = *(const float4*)(yy + 12);
            float4 v4 = *(const float4*)(yy + 16);
            float z[DLAT] = {v0.x, v0.y, v0.z, v0.w, v1.x, v1.y, v1.z, v1.w, v2.x, v2.y};
            float w[DLAT] = {v2.z, v2.w, v3.x, v3.y, v3.z, v3.w, v4.x, v4.y, v4.z, v4.w};
            int kk = nw * 4 + cl;
            const float* Gk = Gs + kk * 100;
            float s = 0.f, wz = 0.f;
#pragma unroll
            for (int a = 0; a < DLAT; ++a) {
                float gz = 0.f;
#pragma unroll
                for (int b2 = 0; b2 < DLAT; ++b2) gz = fmaf(Gk[a * DLAT + b2], z[b2], gz);
                s  = fmaf(z[a], gz, s);
                wz = fmaf(w[a], z[a], wz);
            }
            objl[mw * 32 + m * 16 + rowl][kk] = s - 2.f * wz + lregs[kk];
        }
        __syncthreads();
    }

    if (wv == 0) {
        float mn = objl[lane][0];
#pragma unroll
        for (int k = 1; k < KCLUST; ++k) mn = fminf(mn, objl[lane][k]);
        float v = mn + rowsq_s[lane];
#pragma unroll
        for (int off = 32; off > 0; off >>= 1) v += __shfl_down(v, off);
        if (lane == 0)
            __hip_atomic_store(&parts[bid], v, __ATOMIC_RELAXED, __HIP_MEMORY_SCOPE_AGENT);
    }

    __threadfence();
    grid.sync();

    // ---- Phase C: block 0 reduces 256 partials (fixed order => deterministic)
    if (bid == 0 && wv == 0) {
        float s = __hip_atomic_load(&parts[lane],       __ATOMIC_RELAXED, __HIP_MEMORY_SCOPE_AGENT)
                + __hip_atomic_load(&parts[lane + 64],  __ATOMIC_RELAXED, __HIP_MEMORY_SCOPE_AGENT)
                + __hip_atomic_load(&parts[lane + 128], __ATOMIC_RELAXED, __HIP_MEMORY_SCOPE_AGENT)
                + __hip_atomic_load(&parts[lane + 192], __ATOMIC_RELAXED, __HIP_MEMORY_SCOPE_AGENT);
#pragma unroll
        for (int off = 32; off > 0; off >>= 1) s += __shfl_down(s, off);
        if (lane == 0) out[0] = s * (1.0f / BATCH);
    }
}

// ==================== fallback path (round-10 proven, 2 dispatches) ====================
__global__ __launch_bounds__(256) void fb_setup(const float* __restrict__ Us,
                                                const float* __restrict__ Vs,
                                                short* __restrict__ wpack,
                                                float* __restrict__ G,
                                                float* __restrict__ lreg,
                                                unsigned* __restrict__ cnt) {
    int b = blockIdx.x;
    int tid = threadIdx.x;
    if (b == 0 && tid == 0)
        __hip_atomic_store(cnt, 0u, __ATOMIC_RELEASE, __HIP_MEMORY_SCOPE_AGENT);
    if (b < 80) {
        pack_w_row(Us, Vs, wpack, b * 256 + tid);
    } else {
        __shared__ float red[256];
        int k = b - 80;
        const float* Uk = Us + (size_t)k * DAMB * DLAT;
        const float* Vk = Vs + (size_t)k * DLAT * DAMB;
        float s = 0.f;
        for (int i = tid; i < DAMB * DLAT; i += 256) {
            float a = Uk[i], bb = Vk[i];
            s += a * a + bb * bb;
        }
        red[tid] = s;
        __syncthreads();
        for (int st = 128; st > 0; st >>= 1) {
            if (tid < st) red[tid] += red[tid + st];
            __syncthreads();
        }
        if (tid == 0) lreg[k] = LAMBDA * 0.5f * red[0];
        if (tid < DLAT * DLAT) {
            int i = tid / DLAT, j = tid % DLAT;
            float g = 0.f;
            for (int Dv = 0; Dv < DAMB; ++Dv)
                g += Uk[Dv * DLAT + i] * Uk[Dv * DLAT + j];
            G[k * 100 + tid] = g;
        }
    }
}

__global__ __launch_bounds__(NTHREADS) void fb_main(const float* __restrict__ x,
                                                    const short* __restrict__ wpack,
                                                    const float* __restrict__ G,
                                                    const float* __restrict__ lreg,
                                                    float* __restrict__ parts,
                                                    unsigned* __restrict__ cnt,
                                                    float* __restrict__ out) {
    __shared__ __align__(16) char a_region[65536];
    __shared__ __align__(16) char b_region[2 * CHB];
    __shared__ float Gs[KCLUST * 100];
    __shared__ float lregs[KCLUST];
    __shared__ float rsqp[BM][8];
    __shared__ float rowsq_s[BM];
    __shared__ int   isLast;

    short* a_lds = (short*)a_region;
    float* sbuf  = (float*)a_region;
    float (*objl)[17] = (float(*)[17])b_region;

    const int tid  = threadIdx.x;
    const int lane = tid & 63;
    const int wv   = tid >> 6;
    const int mw   = wv >> 2;
    const int nw   = wv & 3;
    const int row0 = blockIdx.x * BM;

    {
        const int srow = tid >> 3;
        const int sc   = tid & 7;
        const int mt   = srow >> 4;
        const int rlo  = srow & 15;
        const float* xr = x + (size_t)(row0 + srow) * DAMB;
        float rs = 0.f;
#pragma unroll
        for (int i = 0; i < 8; ++i) {
            int k8 = sc + 8 * i;
            float4 v0 = *(const float4*)(xr + k8 * 8);
            float4 v1 = *(const float4*)(xr + k8 * 8 + 4);
            rs += v0.x * v0.x + v0.y * v0.y + v0.z * v0.z + v0.w * v0.w
                + v1.x * v1.x + v1.y * v1.y + v1.z * v1.z + v1.w * v1.w;
            short8 sv;
            sv[0] = f2bf(v0.x); sv[1] = f2bf(v0.y); sv[2] = f2bf(v0.z); sv[3] = f2bf(v0.w);
            sv[4] = f2bf(v1.x); sv[5] = f2bf(v1.y); sv[6] = f2bf(v1.z); sv[7] = f2bf(v1.w);
            int ks = k8 >> 2, lh = k8 & 3;
            int ln = (lh << 4) | rlo;
            *(short8*)&a_lds[((mt * NKS + ks) * 64 + ln) * 8] = sv;
        }
        rsqp[srow][sc] = rs;
    }
    for (int i = tid; i < KCLUST * 100; i += NTHREADS) Gs[i] = G[i];
    if (tid < KCLUST) lregs[tid] = lreg[tid];
    __syncthreads();
    if (tid < BM) {
        float s = 0.f;
#pragma unroll
        for (int j = 0; j < 8; ++j) s += rsqp[tid][j];
        rowsq_s[tid] = s;
    }

    f32x4 acc[2][5];
#pragma unroll
    for (int m = 0; m < 2; ++m)
#pragma unroll
        for (int j = 0; j < 5; ++j) acc[m][j] = (f32x4)0.f;

    const char* wsrc = (const char*)wpack;
    const int soff = (wv * 5) * 1024 + lane * 16;

#define ISSUE(c) do { \
        const char* s_ = wsrc + (size_t)(c) * CHB + soff; \
        char* d_ = b_region + ((c) & 1) * CHB + soff; \
        gload_lds16(s_ + 0,    d_ + 0); \
        gload_lds16(s_ + 1024, d_ + 1024); \
        gload_lds16(s_ + 2048, d_ + 2048); \
        gload_lds16(s_ + 3072, d_ + 3072); \
        gload_lds16(s_ + 4096, d_ + 4096); \
        __builtin_amdgcn_sched_barrier(0); \
    } while (0)

#define KSTEP(c, VM) do { \
        waitv<VM>(); \
        __builtin_amdgcn_s_barrier(); \
        __builtin_amdgcn_sched_barrier(0); \
        const short* B_ = (const short*)(b_region + ((c) & 1) * CHB); \
        _Pragma("unroll") \
        for (int ksl = 0; ksl < 2; ++ksl) { \
            short8 a0 = *(short8*)&a_lds[(((mw * 2 + 0) * NKS + (c) * 2 + ksl) * 64 + lane) * 8]; \
            short8 a1 = *(short8*)&a_lds[(((mw * 2 + 1) * NKS + (c) * 2 + ksl) * 64 + lane) * 8]; \
            _Pragma("unroll") \
            for (int j = 0; j < 5; ++j) { \
                short8 bf = *(short8*)&B_[((ksl * NNT + nw * 5 + j) * 64 + lane) * 8]; \
                acc[0][j] = __builtin_amdgcn_mfma_f32_16x16x32_bf16(a0, bf, acc[0][j], 0, 0, 0); \
                acc[1][j] = __builtin_amdgcn_mfma_f32_16x16x32_bf16(a1, bf, acc[1][j], 0, 0, 0); \
            } \
        } \
        __builtin_amdgcn_sched_barrier(0); \
        __builtin_amdgcn_s_barrier(); \
        __builtin_amdgcn_sched_barrier(0); \
    } while (0)

    ISSUE(0); ISSUE(1);
    KSTEP(0, 5); ISSUE(2);
    KSTEP(1, 5); ISSUE(3);
    KSTEP(2, 5); ISSUE(4);
    KSTEP(3, 5); ISSUE(5);
    KSTEP(4, 5); ISSUE(6);
    KSTEP(5, 5); ISSUE(7);
    KSTEP(6, 5);
    KSTEP(7, 0);

#undef KSTEP
#undef ISSUE

    const int stro = wv * (16 * SSTR);
#pragma unroll
    for (int m = 0; m < 2; ++m) {
        int rowb = (lane >> 4) * 4;
#pragma unroll
        for (int j = 0; j < 5; ++j) {
            int colb = j * 16 + (lane & 15);
#pragma unroll
            for (int r = 0; r < 4; ++r)
                sbuf[stro + (rowb + r) * SSTR + colb] = acc[m][j][r];
        }
        {
            int rowl = lane >> 2;
            int cl   = lane & 3;
            const float* yy = sbuf + stro + rowl * SSTR + cl * 20;
            float4 v0 = *(const float4*)(yy + 0);
            float4 v1 = *(const float4*)(yy + 4);
            float4 v2 = *(const float4*)(yy + 8);
            float4 v3 = *(const float4*)(yy + 12);
            float4 v4 = *(const float4*)(yy + 16);
            float z[DLAT] = {v0.x, v0.y, v0.z, v0.w, v1.x, v1.y, v1.z, v1.w, v2.x, v2.y};
            float w[DLAT] = {v2.z, v2.w, v3.x, v3.y, v3.z, v3.w, v4.x, v4.y, v4.z, v4.w};
            int kk = nw * 4 + cl;
            const float* Gk = Gs + kk * 100;
            float s = 0.f, wz = 0.f;
#pragma unroll
            for (int a = 0; a < DLAT; ++a) {
                float gz = 0.f;
#pragma unroll
                for (int b2 = 0; b2 < DLAT; ++b2) gz = fmaf(Gk[a * DLAT + b2], z[b2], gz);
                s  = fmaf(z[a], gz, s);
                wz = fmaf(w[a], z[a], wz);
            }
            objl[mw * 32 + m * 16 + rowl][kk] = s - 2.f * wz + lregs[kk];
        }
        __syncthreads();
    }

    if (wv == 0) {
        float mn = objl[lane][0];
#pragma unroll
        for (int k = 1; k < KCLUST; ++k) mn = fminf(mn, objl[lane][k]);
        float v = mn + rowsq_s[lane];
#pragma unroll
        for (int off = 32; off > 0; off >>= 1) v += __shfl_down(v, off);
        if (lane == 0) {
            __hip_atomic_store(&parts[blockIdx.x], v, __ATOMIC_RELEASE,
                               __HIP_MEMORY_SCOPE_AGENT);
            unsigned prev = __hip_atomic_fetch_add(cnt, 1u, __ATOMIC_ACQ_REL,
                                                   __HIP_MEMORY_SCOPE_AGENT);
            isLast = (prev == NBLK - 1);
        }
    }
    __syncthreads();

    if (isLast && wv == 0) {
        float s = 0.f;
#pragma unroll
        for (int q = 0; q < NBLK / 64; ++q)
            s += __hip_atomic_load(&parts[lane + q * 64], __ATOMIC_RELAXED,
                                   __HIP_MEMORY_SCOPE_AGENT);
#pragma unroll
        for (int off = 32; off > 0; off >>= 1) s += __shfl_down(s, off);
        if (lane == 0) out[0] = s * (1.0f / BATCH);
    }
}

extern "C" void kernel_launch(void* const* d_in, const int* in_sizes, int n_in,
                              void* d_out, int out_size, void* d_ws, size_t ws_size,
                              hipStream_t stream) {
    const float* x  = (const float*)d_in[0];   // 16384 x 512
    const float* Us = (const float*)d_in[1];   // 16 x 512 x 10
    const float* Vs = (const float*)d_in[2];   // 16 x 10 x 512
    float* out = (float*)d_out;

    // workspace: wpack[20480*8] shorts (320KB) | G[1600] | lreg[16] | parts[256] | cnt
    short* wpack   = (short*)d_ws;
    float* G       = (float*)(wpack + NKS * NNT * 64 * 8);
    float* lreg    = G + KCLUST * 100;
    float* parts   = lreg + KCLUST;
    unsigned* cnt  = (unsigned*)(parts + NBLK);

    void* args[] = {(void*)&x, (void*)&Us, (void*)&Vs, (void*)&wpack,
                    (void*)&G, (void*)&lreg, (void*)&parts, (void*)&out};
    hipError_t e = hipLaunchCooperativeKernel((const void*)fused_k,
                                              dim3(NBLK), dim3(NTHREADS),
                                              args, 0, stream);
    if (e != hipSuccess) {
        // fallback: proven 2-dispatch path (also clears sticky error state)
        (void)hipGetLastError();
        fb_setup<<<96, 256, 0, stream>>>(Us, Vs, wpack, G, lreg, cnt);
        fb_main<<<NBLK, NTHREADS, 0, stream>>>(x, wpack, G, lreg, parts, cnt, out);
    }
}

// Round 14
// 65.681 us; speedup vs baseline: 2.8757x; 2.8757x over previous
//
#include <hip/hip_runtime.h>

// K-manifold AE cluster objective — ROUND 14: ONE dispatch, flag-barrier.
// out = mean_b min_k [ ||x_b||^2 - 2 w.z + z^T G z + lamb*reg_k ]
// 128 blocks x 512 thr, 148KB LDS -> 1 block/CU, 128 <= 256 CUs: all co-resident,
// so device-scope flag spin is deadlock-free. Phase A: A-stage + distributed
// W-pack (160 rows/block) + G/lreg (blocks 0-15) -> flag barrier. Phase B: r9's
// proven asm-vmcnt MFMA loop + wave-local epilogue. Block 0 reduces partials.

#define KCLUST   16
#define DAMB     512
#define DLAT     10
#define BATCH    16384
#define LAMBDA   0.01f

#define BM       128           // batch rows per block (8 m-tiles)
#define NTHREADS 512           // 8 waves: 2M x 4N
#define NKS      16            // 512/32 k-steps
#define NNT      20            // 320/16 n-tiles
#define NBLK     (BATCH / BM)  // 128
#define SSTR     84            // epilogue strip stride (floats)
#define WMAGIC   0x13579BDFu
#define PMAGIC   0x2468ACE0u

typedef __attribute__((ext_vector_type(8))) short short8;
typedef __attribute__((ext_vector_type(4))) float f32x4;

__device__ inline short f2bf(float f) {
    unsigned u = __builtin_bit_cast(unsigned, f);
    unsigned r = (u + 0x7FFFu + ((u >> 16) & 1u)) >> 16;
    return (short)r;
}

// W fragment-row packer: idx in [0, 20480)
// wpack[ks][nt][lane][8]: lane l holds B[k = ks*32 + (l>>4)*8 + j][col = nt*16 + (l&15)]
__device__ __forceinline__ void pack_w_row(const float* __restrict__ Us,
                                           const float* __restrict__ Vs,
                                           short* __restrict__ wpack, int idx) {
    int ks   = idx / (NNT * 64);
    int rem  = idx % (NNT * 64);
    int nt   = rem / 64;
    int lane = rem % 64;
    int col  = nt * 16 + (lane & 15);
    int cl   = col / 20;
    int c    = col % 20;
    short8 sv;
#pragma unroll
    for (int j = 0; j < 8; ++j) {
        int k = ks * 32 + (lane >> 4) * 8 + j;
        float v;
        if (c < DLAT) v = Vs[(size_t)cl * DLAT * DAMB + c * DAMB + k];
        else          v = Us[(size_t)cl * DAMB * DLAT + k * DLAT + (c - DLAT)];
        sv[j] = f2bf(v);
    }
    *(short8*)&wpack[(size_t)idx * 8] = sv;
}

// raw global load the compiler cannot sink/merge
#define GLOAD(dst, addr) \
    asm volatile("global_load_dwordx4 %0, %1, off" : "=&v"(dst) : "v"(addr) : "memory")

template <int N> __device__ __forceinline__ void waitv() {
    if constexpr (N == 0)       asm volatile("s_waitcnt vmcnt(0)"  ::: "memory");
    else if constexpr (N == 5)  asm volatile("s_waitcnt vmcnt(5)"  ::: "memory");
    else if constexpr (N == 10) asm volatile("s_waitcnt vmcnt(10)" ::: "memory");
    else                        asm volatile("s_waitcnt vmcnt(15)" ::: "memory");
    __builtin_amdgcn_sched_barrier(0);   // rule #18
}

// ==================== single fused kernel ====================
__global__ __launch_bounds__(NTHREADS, 2) void fused_k(const float* __restrict__ x,
                                                       const float* __restrict__ Us,
                                                       const float* __restrict__ Vs,
                                                       short* __restrict__ wpack,
                                                       float* __restrict__ G,
                                                       float* __restrict__ lreg,
                                                       float* __restrict__ parts,
                                                       unsigned* __restrict__ wflags,
                                                       unsigned* __restrict__ pflags,
                                                       float* __restrict__ out) {
    __shared__ __align__(16) char uni[128 * 1024];    // A frags; epilogue strips
    __shared__ float Gs[KCLUST * 100];                // 6.4 KB
    __shared__ float lregs[KCLUST];
    __shared__ float gpart[500];
    __shared__ float sred[8];
    __shared__ float rsqp[BM][4];
    __shared__ float rowsq_s[BM];
    __shared__ float objl[BM][17];
    __shared__ float red[BM];

    short* a_lds = (short*)uni;                 // [mt 0..7][ks][lane][8], 128 KB
    float* sbuf  = (float*)uni;                 // [wave][32][SSTR]

    const int tid  = threadIdx.x;
    const int lane = tid & 63;
    const int wv   = tid >> 6;                  // 0..7
    const int mw   = wv >> 2;                   // 0..1: m-tiles mw*4 .. +3
    const int nw   = wv & 3;                    // 0..3: n-tiles nw*5 .. +4
    const int bid  = blockIdx.x;
    const int row0 = bid * BM;

    // ---- Phase A1: distributed W pack (160 fragment-rows per block)
    if (tid < 160) pack_w_row(Us, Vs, wpack, bid * 160 + tid);

    // ---- Phase A2: stage A (fp32 -> bf16, fragment order) + exact fp32 rowsq
    {
        const int srow = tid >> 2;              // 0..127
        const int sc   = tid & 3;               // 0..3
        const int mt   = srow >> 4;
        const int rlo  = srow & 15;
        const float* xr = x + (size_t)(row0 + srow) * DAMB;
        float rs = 0.f;
#pragma unroll
        for (int i = 0; i < 16; ++i) {
            int k8 = sc + 4 * i;                // 8-float group, 0..63
            float4 v0 = *(const float4*)(xr + k8 * 8);
            float4 v1 = *(const float4*)(xr + k8 * 8 + 4);
            rs += v0.x * v0.x + v0.y * v0.y + v0.z * v0.z + v0.w * v0.w
                + v1.x * v1.x + v1.y * v1.y + v1.z * v1.z + v1.w * v1.w;
            short8 sv;
            sv[0] = f2bf(v0.x); sv[1] = f2bf(v0.y); sv[2] = f2bf(v0.z); sv[3] = f2bf(v0.w);
            sv[4] = f2bf(v1.x); sv[5] = f2bf(v1.y); sv[6] = f2bf(v1.z); sv[7] = f2bf(v1.w);
            int ks = k8 >> 2, lh = k8 & 3;
            int ln = (lh << 4) | rlo;
            *(short8*)&a_lds[((mt * NKS + ks) * 64 + ln) * 8] = sv;
        }
        rsqp[srow][sc] = rs;
    }

    // ---- Phase A3: blocks 0..15 compute lreg + G for cluster bid
    if (bid < KCLUST) {
        const float* Uk = Us + (size_t)bid * DAMB * DLAT;
        const float* Vk = Vs + (size_t)bid * DLAT * DAMB;
        float s = 0.f;
        for (int i = tid; i < DAMB * DLAT; i += NTHREADS) {
            float a = Uk[i], b = Vk[i];
            s += a * a + b * b;
        }
#pragma unroll
        for (int off = 32; off > 0; off >>= 1) s += __shfl_down(s, off);
        if (lane == 0) sred[wv] = s;
        __syncthreads();
        if (tid == 0) {
            float t = 0.f;
#pragma unroll
            for (int j = 0; j < 8; ++j) t += sred[j];
            lreg[bid] = (LAMBDA * 0.5f) * t;
        }
        if (tid < 500) {
            int e = tid / 5, dp = tid % 5;
            int i = e / DLAT, j = e % DLAT;
            int d0 = dp * 102 + (dp < 2 ? dp : 2);
            int d1 = d0 + 102 + (dp < 2 ? 1 : 0);
            float g = 0.f;
            for (int d = d0; d < d1; ++d)
                g = fmaf(Uk[d * DLAT + i], Uk[d * DLAT + j], g);
            gpart[tid] = g;
        }
        __syncthreads();
        if (tid < 100) {
            float g = gpart[tid * 5] + gpart[tid * 5 + 1] + gpart[tid * 5 + 2]
                    + gpart[tid * 5 + 3] + gpart[tid * 5 + 4];
            G[bid * 100 + tid] = g;
        }
    }
    __syncthreads();
    if (tid < BM)
        rowsq_s[tid] = rsqp[tid][0] + rsqp[tid][1] + rsqp[tid][2] + rsqp[tid][3];

    // ---- flag barrier: publish this block's W/G contribution; wait for all 128.
    // (All 128 blocks are co-resident: 148KB LDS => 1 block/CU, grid 128 <= 256 CUs.
    //  On replays flags may already be WMAGIC: benign — rewrites store identical bytes.)
    if (tid == 0) {
        __threadfence();
        __hip_atomic_store(&wflags[bid], WMAGIC, __ATOMIC_RELEASE, __HIP_MEMORY_SCOPE_AGENT);
    }
    if (wv == 0) {
        for (;;) {
            unsigned a = __hip_atomic_load(&wflags[lane],      __ATOMIC_ACQUIRE, __HIP_MEMORY_SCOPE_AGENT);
            unsigned b = __hip_atomic_load(&wflags[lane + 64], __ATOMIC_ACQUIRE, __HIP_MEMORY_SCOPE_AGENT);
            if (__all(a == WMAGIC && b == WMAGIC)) break;
            __builtin_amdgcn_s_sleep(8);
        }
    }
    __syncthreads();

    // ---- Phase B0: stage G/lreg to LDS
    for (int i = tid; i < KCLUST * 100; i += NTHREADS) Gs[i] = G[i];
    if (tid < KCLUST) lregs[tid] = lreg[tid];
    __syncthreads();

    // ---- Phase B1: K loop (r9-proven: asm B loads, 4-deep ring, counted vmcnt)
    f32x4 acc[4][5];
#pragma unroll
    for (int m = 0; m < 4; ++m)
#pragma unroll
        for (int j = 0; j < 5; ++j) acc[m][j] = (f32x4)0.f;

    const char* wbase = (const char*)wpack + ((size_t)(nw * 5) * 64 + lane) * 16;
    short8 bb[4][5];

#define BADDR(ks, j) (wbase + (size_t)((ks) * 20480 + (j) * 1024))
#define LOADG(ks) do { \
        GLOAD(bb[(ks) & 3][0], BADDR(ks, 0)); \
        GLOAD(bb[(ks) & 3][1], BADDR(ks, 1)); \
        GLOAD(bb[(ks) & 3][2], BADDR(ks, 2)); \
        GLOAD(bb[(ks) & 3][3], BADDR(ks, 3)); \
        GLOAD(bb[(ks) & 3][4], BADDR(ks, 4)); \
    } while (0)

    LOADG(0); LOADG(1); LOADG(2); LOADG(3);

#define STEP(ks, VM) do { \
        short8 a0 = *(short8*)&a_lds[(((mw * 4 + 0) * NKS + (ks)) * 64 + lane) * 8]; \
        short8 a1 = *(short8*)&a_lds[(((mw * 4 + 1) * NKS + (ks)) * 64 + lane) * 8]; \
        short8 a2 = *(short8*)&a_lds[(((mw * 4 + 2) * NKS + (ks)) * 64 + lane) * 8]; \
        short8 a3 = *(short8*)&a_lds[(((mw * 4 + 3) * NKS + (ks)) * 64 + lane) * 8]; \
        waitv<VM>(); \
        acc[0][0] = __builtin_amdgcn_mfma_f32_16x16x32_bf16(a0, bb[(ks) & 3][0], acc[0][0], 0, 0, 0); \
        acc[1][0] = __builtin_amdgcn_mfma_f32_16x16x32_bf16(a1, bb[(ks) & 3][0], acc[1][0], 0, 0, 0); \
        acc[2][0] = __builtin_amdgcn_mfma_f32_16x16x32_bf16(a2, bb[(ks) & 3][0], acc[2][0], 0, 0, 0); \
        acc[3][0] = __builtin_amdgcn_mfma_f32_16x16x32_bf16(a3, bb[(ks) & 3][0], acc[3][0], 0, 0, 0); \
        acc[0][1] = __builtin_amdgcn_mfma_f32_16x16x32_bf16(a0, bb[(ks) & 3][1], acc[0][1], 0, 0, 0); \
        acc[1][1] = __builtin_amdgcn_mfma_f32_16x16x32_bf16(a1, bb[(ks) & 3][1], acc[1][1], 0, 0, 0); \
        acc[2][1] = __builtin_amdgcn_mfma_f32_16x16x32_bf16(a2, bb[(ks) & 3][1], acc[2][1], 0, 0, 0); \
        acc[3][1] = __builtin_amdgcn_mfma_f32_16x16x32_bf16(a3, bb[(ks) & 3][1], acc[3][1], 0, 0, 0); \
        acc[0][2] = __builtin_amdgcn_mfma_f32_16x16x32_bf16(a0, bb[(ks) & 3][2], acc[0][2], 0, 0, 0); \
        acc[1][2] = __builtin_amdgcn_mfma_f32_16x16x32_bf16(a1, bb[(ks) & 3][2], acc[1][2], 0, 0, 0); \
        acc[2][2] = __builtin_amdgcn_mfma_f32_16x16x32_bf16(a2, bb[(ks) & 3][2], acc[2][2], 0, 0, 0); \
        acc[3][2] = __builtin_amdgcn_mfma_f32_16x16x32_bf16(a3, bb[(ks) & 3][2], acc[3][2], 0, 0, 0); \
        acc[0][3] = __builtin_amdgcn_mfma_f32_16x16x32_bf16(a0, bb[(ks) & 3][3], acc[0][3], 0, 0, 0); \
        acc[1][3] = __builtin_amdgcn_mfma_f32_16x16x32_bf16(a1, bb[(ks) & 3][3], acc[1][3], 0, 0, 0); \
        acc[2][3] = __builtin_amdgcn_mfma_f32_16x16x32_bf16(a2, bb[(ks) & 3][3], acc[2][3], 0, 0, 0); \
        acc[3][3] = __builtin_amdgcn_mfma_f32_16x16x32_bf16(a3, bb[(ks) & 3][3], acc[3][3], 0, 0, 0); \
        acc[0][4] = __builtin_amdgcn_mfma_f32_16x16x32_bf16(a0, bb[(ks) & 3][4], acc[0][4], 0, 0, 0); \
        acc[1][4] = __builtin_amdgcn_mfma_f32_16x16x32_bf16(a1, bb[(ks) & 3][4], acc[1][4], 0, 0, 0); \
        acc[2][4] = __builtin_amdgcn_mfma_f32_16x16x32_bf16(a2, bb[(ks) & 3][4], acc[2][4], 0, 0, 0); \
        acc[3][4] = __builtin_amdgcn_mfma_f32_16x16x32_bf16(a3, bb[(ks) & 3][4], acc[3][4], 0, 0, 0); \
        if ((ks) + 4 < NKS) LOADG((ks) + 4); \
    } while (0)

    STEP(0, 15);  STEP(1, 15);  STEP(2, 15);  STEP(3, 15);
    STEP(4, 15);  STEP(5, 15);  STEP(6, 15);  STEP(7, 15);
    STEP(8, 15);  STEP(9, 15);  STEP(10, 15); STEP(11, 15);
    STEP(12, 15); STEP(13, 10); STEP(14, 5);  STEP(15, 0);

#undef STEP
#undef LOADG
#undef BADDR

    __syncthreads();                     // a_lds dead; uni becomes per-wave strips

    // ---- Phase B2: wave-local epilogue (r9-proven)
    const int sboff = wv * (32 * SSTR);
#pragma unroll
    for (int mh = 0; mh < 2; ++mh) {
#pragma unroll
        for (int qq = 0; qq < 2; ++qq) {
            int q = mh * 2 + qq;
            int rowl = qq * 16 + (lane >> 4) * 4;
#pragma unroll
            for (int j = 0; j < 5; ++j) {
                int coll = j * 16 + (lane & 15);
#pragma unroll
                for (int r = 0; r < 4; ++r)
                    sbuf[sboff + (rowl + r) * SSTR + coll] = acc[q][j][r];
            }
        }
        __syncthreads();
#pragma unroll
        for (int it = 0; it < 2; ++it) {
            int i = lane + 64 * it;
            int rowl = i >> 2, cl = i & 3;
            const float* yy = sbuf + sboff + rowl * SSTR + cl * 20;
            float4 v0 = *(const float4*)(yy + 0);
            float4 v1 = *(const float4*)(yy + 4);
            float4 v2 = *(const float4*)(yy + 8);
            float4 v3 = *(const float4*)(yy + 12);
            float4 v4 = *(const float4*)(yy + 16);
            float z[DLAT] = {v0.x, v0.y, v0.z, v0.w, v1.x, v1.y, v1.z, v1.w, v2.x, v2.y};
            float w[DLAT] = {v2.z, v2.w, v3.x, v3.y, v3.z, v3.w, v4.x, v4.y, v4.z, v4.w};
            int kk = nw * 4 + cl;
            const float* Gk = Gs + kk * 100;
            float s = 0.f, wz = 0.f;
#pragma unroll
            for (int a = 0; a < DLAT; ++a) {
                float gz = 0.f;
#pragma unroll
                for (int b2 = 0; b2 < DLAT; ++b2) gz = fmaf(Gk[a * DLAT + b2], z[b2], gz);
                s  = fmaf(z[a], gz, s);
                wz = fmaf(w[a], z[a], wz);
            }
            objl[mw * 64 + mh * 32 + rowl][kk] = s - 2.f * wz + lregs[kk];
        }
        __syncthreads();
    }

    // ---- per-row min + block reduce -> parts[bid] + pflag
    if (tid < BM) {
        float m = objl[tid][0];
#pragma unroll
        for (int k = 1; k < KCLUST; ++k) m = fminf(m, objl[tid][k]);
        red[tid] = m + rowsq_s[tid];
    }
    __syncthreads();
    if (wv == 0) {
        float v = red[lane] + red[lane + 64];
#pragma unroll
        for (int off = 32; off > 0; off >>= 1) v += __shfl_down(v, off);
        if (lane == 0) {
            __hip_atomic_store(&parts[bid], v, __ATOMIC_RELAXED, __HIP_MEMORY_SCOPE_AGENT);
            __threadfence();
            __hip_atomic_store(&pflags[bid], PMAGIC, __ATOMIC_RELEASE, __HIP_MEMORY_SCOPE_AGENT);
        }
    }

    // ---- block 0 reduces all 128 partials (fixed order => deterministic)
    if (bid == 0 && wv == 0) {
        for (;;) {
            unsigned a = __hip_atomic_load(&pflags[lane],      __ATOMIC_ACQUIRE, __HIP_MEMORY_SCOPE_AGENT);
            unsigned b = __hip_atomic_load(&pflags[lane + 64], __ATOMIC_ACQUIRE, __HIP_MEMORY_SCOPE_AGENT);
            if (__all(a == PMAGIC && b == PMAGIC)) break;
            __builtin_amdgcn_s_sleep(8);
        }
        float s = __hip_atomic_load(&parts[lane],      __ATOMIC_RELAXED, __HIP_MEMORY_SCOPE_AGENT)
                + __hip_atomic_load(&parts[lane + 64], __ATOMIC_RELAXED, __HIP_MEMORY_SCOPE_AGENT);
#pragma unroll
        for (int off = 32; off > 0; off >>= 1) s += __shfl_down(s, off);
        if (lane == 0) out[0] = s * (1.0f / BATCH);
    }
}

extern "C" void kernel_launch(void* const* d_in, const int* in_sizes, int n_in,
                              void* d_out, int out_size, void* d_ws, size_t ws_size,
                              hipStream_t stream) {
    const float* x  = (const float*)d_in[0];   // 16384 x 512
    const float* Us = (const float*)d_in[1];   // 16 x 512 x 10
    const float* Vs = (const float*)d_in[2];   // 16 x 10 x 512
    float* out = (float*)d_out;

    // workspace: wpack[20480*8] shorts (320KB) | G[1600] | lreg[16] | parts[128]
    //            | wflags[128] | pflags[128]
    short* wpack    = (short*)d_ws;
    float* G        = (float*)(wpack + NKS * NNT * 64 * 8);
    float* lreg     = G + KCLUST * 100;
    float* parts    = lreg + KCLUST;
    unsigned* wflags = (unsigned*)(parts + NBLK);
    unsigned* pflags = wflags + NBLK;

    fused_k<<<NBLK, NTHREADS, 0, stream>>>(x, Us, Vs, wpack, G, lreg,
                                           parts, wflags, pflags, out);
}

// Round 15
// 45.290 us; speedup vs baseline: 4.1704x; 1.4502x over previous
//
#include <hip/hip_runtime.h>

// K-manifold AE cluster objective, fused, bf16-MFMA GEMM.
// out = mean_b min_k [ ||x_b||^2 - 2 w.z + z^T G z + lamb*reg_k ]
// GEMM: Y[16384][320] = X[16384][512] @ W[512][320] via pre-packed B fragments.
// Round 15: r9 champion (2 dispatches, BM=128, asm-vmcnt B ring) + XCD bid
// swizzle (T1) + s_setprio around MFMA clusters (T5).

#define KCLUST   16
#define DAMB     512
#define DLAT     10
#define BATCH    16384
#define LAMBDA   0.01f

#define BM       128           // batch rows per block (8 m-tiles)
#define NTHREADS 512           // 8 waves: 2M x 4N
#define NKS      16            // 512/32 k-steps
#define NNT      20            // 320/16 n-tiles
#define NBLK     (BATCH / BM)  // 128
#define SSTR     84            // epilogue strip stride (floats)

typedef __attribute__((ext_vector_type(8))) short short8;
typedef __attribute__((ext_vector_type(4))) float f32x4;

__device__ inline short f2bf(float f) {
    unsigned u = __builtin_bit_cast(unsigned, f);
    unsigned r = (u + 0x7FFFu + ((u >> 16) & 1u)) >> 16;
    return (short)r;
}

// ---------------- setup: blocks 0..79 pack W frags; 80..95 compute G/lreg; zero cnt
// wpack[ks][nt][lane][8]: lane l holds B[k = ks*32 + (l>>4)*8 + j][col = nt*16 + (l&15)]
__global__ __launch_bounds__(256) void setup_k(const float* __restrict__ Us,
                                               const float* __restrict__ Vs,
                                               short* __restrict__ wpack,
                                               float* __restrict__ G,
                                               float* __restrict__ lreg,
                                               unsigned* __restrict__ cnt) {
    int b = blockIdx.x;
    int tid = threadIdx.x;
    if (b == 0 && tid == 0)
        __hip_atomic_store(cnt, 0u, __ATOMIC_RELEASE, __HIP_MEMORY_SCOPE_AGENT);
    if (b < 80) {
        int idx  = b * 256 + tid;                  // [0, 16*20*64)
        int ks   = idx / (NNT * 64);
        int rem  = idx % (NNT * 64);
        int nt   = rem / 64;
        int lane = rem % 64;
        int col  = nt * 16 + (lane & 15);
        int cl   = col / 20;
        int c    = col % 20;
        short8 sv;
#pragma unroll
        for (int j = 0; j < 8; ++j) {
            int k = ks * 32 + (lane >> 4) * 8 + j;
            float v;
            if (c < DLAT) v = Vs[(size_t)cl * DLAT * DAMB + c * DAMB + k];
            else          v = Us[(size_t)cl * DAMB * DLAT + k * DLAT + (c - DLAT)];
            sv[j] = f2bf(v);
        }
        *(short8*)&wpack[(size_t)idx * 8] = sv;
    } else {
        __shared__ float red[256];
        int k = b - 80;
        const float* Uk = Us + (size_t)k * DAMB * DLAT;
        const float* Vk = Vs + (size_t)k * DLAT * DAMB;
        float s = 0.f;
        for (int i = tid; i < DAMB * DLAT; i += 256) {
            float a = Uk[i], bb = Vk[i];
            s += a * a + bb * bb;
        }
        red[tid] = s;
        __syncthreads();
        for (int st = 128; st > 0; st >>= 1) {
            if (tid < st) red[tid] += red[tid + st];
            __syncthreads();
        }
        if (tid == 0) lreg[k] = LAMBDA * 0.5f * red[0];
        if (tid < DLAT * DLAT) {
            int i = tid / DLAT, j = tid % DLAT;
            float g = 0.f;
            for (int Dv = 0; Dv < DAMB; ++Dv)
                g += Uk[Dv * DLAT + i] * Uk[Dv * DLAT + j];
            G[k * 100 + tid] = g;
        }
    }
}

// raw global load the compiler cannot sink/merge
#define GLOAD(dst, addr) \
    asm volatile("global_load_dwordx4 %0, %1, off" : "=&v"(dst) : "v"(addr) : "memory")

template <int N> __device__ __forceinline__ void waitv() {
    if constexpr (N == 0)       asm volatile("s_waitcnt vmcnt(0)"  ::: "memory");
    else if constexpr (N == 5)  asm volatile("s_waitcnt vmcnt(5)"  ::: "memory");
    else if constexpr (N == 10) asm volatile("s_waitcnt vmcnt(10)" ::: "memory");
    else                        asm volatile("s_waitcnt vmcnt(15)" ::: "memory");
    __builtin_amdgcn_sched_barrier(0);   // rule #18: keep MFMAs below the wait
}

// ---------------- main kernel
__global__ __launch_bounds__(NTHREADS, 2) void main_k(const float* __restrict__ x,
                                                      const short* __restrict__ wpack,
                                                      const float* __restrict__ G,
                                                      const float* __restrict__ lreg,
                                                      float* __restrict__ parts,
                                                      unsigned* __restrict__ cnt,
                                                      float* __restrict__ out) {
    __shared__ __align__(16) char uni[128 * 1024];    // A frags; later per-wave strips
    __shared__ float Gs[KCLUST * 100];                // 6.4 KB
    __shared__ float lregs[KCLUST];
    __shared__ float rsqp[BM][4];
    __shared__ float rowsq_s[BM];
    __shared__ float objl[BM][17];
    __shared__ float red[BM];
    __shared__ int   isLast;

    short* a_lds = (short*)uni;                 // [mt 0..7][ks][lane][8], 128 KB
    float* sbuf  = (float*)uni;                 // [wave][32][SSTR]

    const int tid  = threadIdx.x;
    const int lane = tid & 63;
    const int wv   = tid >> 6;                  // 0..7
    const int mw   = wv >> 2;                   // 0..1: m-tiles mw*4 .. +3
    const int nw   = wv & 3;                    // 0..3: n-tiles nw*5 .. +4
    // XCD-aware swizzle (T1): 128 % 8 == 0 -> bijective; neighbors share W in L2
    const int bid  = (blockIdx.x & 7) * (NBLK / 8) + (blockIdx.x >> 3);
    const int row0 = bid * BM;

    // ---- stage A (fp32 -> bf16, fragment order) + exact fp32 rowsq; stage G
    {
        const int srow = tid >> 2;              // 0..127
        const int sc   = tid & 3;               // 0..3
        const int mt   = srow >> 4;
        const int rlo  = srow & 15;
        const float* xr = x + (size_t)(row0 + srow) * DAMB;
        float rs = 0.f;
#pragma unroll
        for (int i = 0; i < 16; ++i) {
            int k8 = sc + 4 * i;                // 8-float group, 0..63
            float4 v0 = *(const float4*)(xr + k8 * 8);
            float4 v1 = *(const float4*)(xr + k8 * 8 + 4);
            rs += v0.x * v0.x + v0.y * v0.y + v0.z * v0.z + v0.w * v0.w
                + v1.x * v1.x + v1.y * v1.y + v1.z * v1.z + v1.w * v1.w;
            short8 sv;
            sv[0] = f2bf(v0.x); sv[1] = f2bf(v0.y); sv[2] = f2bf(v0.z); sv[3] = f2bf(v0.w);
            sv[4] = f2bf(v1.x); sv[5] = f2bf(v1.y); sv[6] = f2bf(v1.z); sv[7] = f2bf(v1.w);
            int ks = k8 >> 2, lh = k8 & 3;
            int ln = (lh << 4) | rlo;
            *(short8*)&a_lds[((mt * NKS + ks) * 64 + ln) * 8] = sv;
        }
        rsqp[srow][sc] = rs;
    }
    for (int i = tid; i < KCLUST * 100; i += NTHREADS) Gs[i] = G[i];
    if (tid < KCLUST) lregs[tid] = lreg[tid];
    __syncthreads();                 // drains vmcnt to 0 before asm loads begin
    if (tid < BM)
        rowsq_s[tid] = rsqp[tid][0] + rsqp[tid][1] + rsqp[tid][2] + rsqp[tid][3];

    // ---- K loop: asm B loads, 4-deep group ring, counted vmcnt, setprio'd MFMA
    f32x4 acc[4][5];
#pragma unroll
    for (int m = 0; m < 4; ++m)
#pragma unroll
        for (int j = 0; j < 5; ++j) acc[m][j] = (f32x4)0.f;

    const char* wbase = (const char*)wpack + ((size_t)(nw * 5) * 64 + lane) * 16;
    short8 bb[4][5];

#define BADDR(ks, j) (wbase + (size_t)((ks) * 20480 + (j) * 1024))
#define LOADG(ks) do { \
        GLOAD(bb[(ks) & 3][0], BADDR(ks, 0)); \
        GLOAD(bb[(ks) & 3][1], BADDR(ks, 1)); \
        GLOAD(bb[(ks) & 3][2], BADDR(ks, 2)); \
        GLOAD(bb[(ks) & 3][3], BADDR(ks, 3)); \
        GLOAD(bb[(ks) & 3][4], BADDR(ks, 4)); \
    } while (0)

    LOADG(0); LOADG(1); LOADG(2); LOADG(3);

#define STEP(ks, VM) do { \
        short8 a0 = *(short8*)&a_lds[(((mw * 4 + 0) * NKS + (ks)) * 64 + lane) * 8]; \
        short8 a1 = *(short8*)&a_lds[(((mw * 4 + 1) * NKS + (ks)) * 64 + lane) * 8]; \
        short8 a2 = *(short8*)&a_lds[(((mw * 4 + 2) * NKS + (ks)) * 64 + lane) * 8]; \
        short8 a3 = *(short8*)&a_lds[(((mw * 4 + 3) * NKS + (ks)) * 64 + lane) * 8]; \
        waitv<VM>(); \
        __builtin_amdgcn_s_setprio(1); \
        acc[0][0] = __builtin_amdgcn_mfma_f32_16x16x32_bf16(a0, bb[(ks) & 3][0], acc[0][0], 0, 0, 0); \
        acc[1][0] = __builtin_amdgcn_mfma_f32_16x16x32_bf16(a1, bb[(ks) & 3][0], acc[1][0], 0, 0, 0); \
        acc[2][0] = __builtin_amdgcn_mfma_f32_16x16x32_bf16(a2, bb[(ks) & 3][0], acc[2][0], 0, 0, 0); \
        acc[3][0] = __builtin_amdgcn_mfma_f32_16x16x32_bf16(a3, bb[(ks) & 3][0], acc[3][0], 0, 0, 0); \
        acc[0][1] = __builtin_amdgcn_mfma_f32_16x16x32_bf16(a0, bb[(ks) & 3][1], acc[0][1], 0, 0, 0); \
        acc[1][1] = __builtin_amdgcn_mfma_f32_16x16x32_bf16(a1, bb[(ks) & 3][1], acc[1][1], 0, 0, 0); \
        acc[2][1] = __builtin_amdgcn_mfma_f32_16x16x32_bf16(a2, bb[(ks) & 3][1], acc[2][1], 0, 0, 0); \
        acc[3][1] = __builtin_amdgcn_mfma_f32_16x16x32_bf16(a3, bb[(ks) & 3][1], acc[3][1], 0, 0, 0); \
        acc[0][2] = __builtin_amdgcn_mfma_f32_16x16x32_bf16(a0, bb[(ks) & 3][2], acc[0][2], 0, 0, 0); \
        acc[1][2] = __builtin_amdgcn_mfma_f32_16x16x32_bf16(a1, bb[(ks) & 3][2], acc[1][2], 0, 0, 0); \
        acc[2][2] = __builtin_amdgcn_mfma_f32_16x16x32_bf16(a2, bb[(ks) & 3][2], acc[2][2], 0, 0, 0); \
        acc[3][2] = __builtin_amdgcn_mfma_f32_16x16x32_bf16(a3, bb[(ks) & 3][2], acc[3][2], 0, 0, 0); \
        acc[0][3] = __builtin_amdgcn_mfma_f32_16x16x32_bf16(a0, bb[(ks) & 3][3], acc[0][3], 0, 0, 0); \
        acc[1][3] = __builtin_amdgcn_mfma_f32_16x16x32_bf16(a1, bb[(ks) & 3][3], acc[1][3], 0, 0, 0); \
        acc[2][3] = __builtin_amdgcn_mfma_f32_16x16x32_bf16(a2, bb[(ks) & 3][3], acc[2][3], 0, 0, 0); \
        acc[3][3] = __builtin_amdgcn_mfma_f32_16x16x32_bf16(a3, bb[(ks) & 3][3], acc[3][3], 0, 0, 0); \
        acc[0][4] = __builtin_amdgcn_mfma_f32_16x16x32_bf16(a0, bb[(ks) & 3][4], acc[0][4], 0, 0, 0); \
        acc[1][4] = __builtin_amdgcn_mfma_f32_16x16x32_bf16(a1, bb[(ks) & 3][4], acc[1][4], 0, 0, 0); \
        acc[2][4] = __builtin_amdgcn_mfma_f32_16x16x32_bf16(a2, bb[(ks) & 3][4], acc[2][4], 0, 0, 0); \
        acc[3][4] = __builtin_amdgcn_mfma_f32_16x16x32_bf16(a3, bb[(ks) & 3][4], acc[3][4], 0, 0, 0); \
        __builtin_amdgcn_s_setprio(0); \
        if ((ks) + 4 < NKS) LOADG((ks) + 4); \
    } while (0)

    STEP(0, 15);  STEP(1, 15);  STEP(2, 15);  STEP(3, 15);
    STEP(4, 15);  STEP(5, 15);  STEP(6, 15);  STEP(7, 15);
    STEP(8, 15);  STEP(9, 15);  STEP(10, 15); STEP(11, 15);
    STEP(12, 15); STEP(13, 10); STEP(14, 5);  STEP(15, 0);

#undef STEP
#undef LOADG
#undef BADDR

    __syncthreads();                     // a_lds dead; uni becomes per-wave strips

    // ---- epilogue, wave-local: wave (mw,nw) owns rows mw*64..+63, clusters nw*4..+3
    const int sboff = wv * (32 * SSTR);
#pragma unroll
    for (int mh = 0; mh < 2; ++mh) {
#pragma unroll
        for (int qq = 0; qq < 2; ++qq) {
            int q = mh * 2 + qq;
            int rowl = qq * 16 + (lane >> 4) * 4;
#pragma unroll
            for (int j = 0; j < 5; ++j) {
                int coll = j * 16 + (lane & 15);
#pragma unroll
                for (int r = 0; r < 4; ++r)
                    sbuf[sboff + (rowl + r) * SSTR + coll] = acc[q][j][r];
            }
        }
        __syncthreads();                 // cross-lane strip visibility
#pragma unroll
        for (int it = 0; it < 2; ++it) {
            int i = lane + 64 * it;
            int rowl = i >> 2, cl = i & 3;
            const float* yy = sbuf + sboff + rowl * SSTR + cl * 20;
            float4 v0 = *(const float4*)(yy + 0);
            float4 v1 = *(const float4*)(yy + 4);
            float4 v2 = *(const float4*)(yy + 8);
            float4 v3 = *(const float4*)(yy + 12);
            float4 v4 = *(const float4*)(yy + 16);
            float z[DLAT] = {v0.x, v0.y, v0.z, v0.w, v1.x, v1.y, v1.z, v1.w, v2.x, v2.y};
            float w[DLAT] = {v2.z, v2.w, v3.x, v3.y, v3.z, v3.w, v4.x, v4.y, v4.z, v4.w};
            int kk = nw * 4 + cl;
            const float* Gk = Gs + kk * 100;
            float s = 0.f, wz = 0.f;
#pragma unroll
            for (int a = 0; a < DLAT; ++a) {
                float gz = 0.f;
#pragma unroll
                for (int b2 = 0; b2 < DLAT; ++b2) gz = fmaf(Gk[a * DLAT + b2], z[b2], gz);
                s  = fmaf(z[a], gz, s);
                wz = fmaf(w[a], z[a], wz);
            }
            objl[mw * 64 + mh * 32 + rowl][kk] = s - 2.f * wz + lregs[kk];
        }
        __syncthreads();                 // strip reads done before next half's writes
    }

    // ---- per-row min + reduce
    if (tid < BM) {
        float m = objl[tid][0];
#pragma unroll
        for (int k = 1; k < KCLUST; ++k) m = fminf(m, objl[tid][k]);
        red[tid] = m + rowsq_s[tid];
    }
    __syncthreads();
    if (wv == 0) {
        float v = red[lane] + red[lane + 64];
#pragma unroll
        for (int off = 32; off > 0; off >>= 1) v += __shfl_down(v, off);
        if (lane == 0) {
            __hip_atomic_store(&parts[bid], v, __ATOMIC_RELEASE,
                               __HIP_MEMORY_SCOPE_AGENT);
            unsigned prev = __hip_atomic_fetch_add(cnt, 1u, __ATOMIC_ACQ_REL,
                                                   __HIP_MEMORY_SCOPE_AGENT);
            isLast = (prev == NBLK - 1);
        }
    }
    __syncthreads();

    // ---- last block reduces all 128 partials (fixed-order => deterministic)
    if (isLast && wv == 0) {
        float s = __hip_atomic_load(&parts[lane], __ATOMIC_RELAXED, __HIP_MEMORY_SCOPE_AGENT)
                + __hip_atomic_load(&parts[lane + 64], __ATOMIC_RELAXED, __HIP_MEMORY_SCOPE_AGENT);
#pragma unroll
        for (int off = 32; off > 0; off >>= 1) s += __shfl_down(s, off);
        if (lane == 0) out[0] = s * (1.0f / BATCH);
    }
}

extern "C" void kernel_launch(void* const* d_in, const int* in_sizes, int n_in,
                              void* d_out, int out_size, void* d_ws, size_t ws_size,
                              hipStream_t stream) {
    const float* x  = (const float*)d_in[0];   // 16384 x 512
    const float* Us = (const float*)d_in[1];   // 16 x 512 x 10
    const float* Vs = (const float*)d_in[2];   // 16 x 10 x 512
    float* out = (float*)d_out;

    // workspace: wpack[20480*8] shorts (320KB) | G[1600] | lreg[16] | parts[128] | cnt
    short* wpack   = (short*)d_ws;
    float* G       = (float*)(wpack + NKS * NNT * 64 * 8);
    float* lreg    = G + KCLUST * 100;
    float* parts   = lreg + KCLUST;
    unsigned* cnt  = (unsigned*)(parts + NBLK);

    setup_k<<<96, 256, 0, stream>>>(Us, Vs, wpack, G, lreg, cnt);
    main_k<<<NBLK, NTHREADS, 0, stream>>>(x, wpack, G, lreg, parts, cnt, out);
}